// Round 12
// baseline (2417.037 us; speedup 1.0000x reference)
//
#include <hip/hip_runtime.h>
#include <math.h>

#define DIN   192
#define HD    256
#define ROWS  64
#define THREADS 256
#define LSTR  256

typedef __bf16 bf16_t;
typedef bf16_t bf16x8 __attribute__((ext_vector_type(8)));
typedef unsigned short u16x8 __attribute__((ext_vector_type(8)));
typedef float  f32x16 __attribute__((ext_vector_type(16)));

static __device__ __forceinline__ f32x16 mfma32(bf16x8 a, bf16x8 b, f32x16 c) {
  return __builtin_amdgcn_mfma_f32_32x32x16_bf16(a, b, c, 0, 0, 0);
}
static __device__ __forceinline__ unsigned short f2bfu(float f) {
  bf16_t h = (bf16_t)f; unsigned short u; __builtin_memcpy(&u, &h, 2); return u;
}
static __device__ __forceinline__ float bfu2f(unsigned short u) {
  unsigned x = ((unsigned)u) << 16; float f; __builtin_memcpy(&f, &x, 4); return f;
}
static __device__ __forceinline__ unsigned pk2(float a, float b) {
  return (unsigned)f2bfu(a) | ((unsigned)f2bfu(b) << 16);
}
static __device__ __forceinline__ float lo16(unsigned u) { return bfu2f((unsigned short)(u & 0xffff)); }
static __device__ __forceinline__ float hi16(unsigned u) { return bfu2f((unsigned short)(u >> 16)); }
static __device__ __forceinline__ float sigm(float x) {
  return __builtin_amdgcn_rcpf(1.f + __expf(-x));
}
// XOR-swizzled LDS element index (b16 granularity)
static __device__ __forceinline__ int lidx(int row, int col) {
  return row * LSTR + (col ^ ((row & 7) << 3));
}
// C-layout row for 32x32 MFMA (m74/m101): row = (r&3) + 8*(r>>2) + 4*kg
static __device__ __forceinline__ int crow(int r, int kg) {
  return (r & 3) + 8 * (r >> 2) + 4 * kg;
}

// bf16 weight regions (elements) in d_ws after scores buffer.
// Fragment order: ((tile*KS + ks)*64 + lane)*8 + j; tile=ocol>>5,
// lane=kg*32+(ocol&31), k=ks*16+kg*8+j. out_w padded 4->32 cols.
#define OFF_WSW1 0
#define OFF_WSS1 49152
#define OFF_WSG1 98304
#define OFF_WSC1 147456
#define OFF_WSW2 212992
#define OFF_WSS2 278528
#define OFF_WSG2 344064
#define OFF_WSC2 409600
#define OFF_WOUT 475136
#define NGRP_REORD 59392
#define NGRP_ALL   60416

__global__ void iab_wconv_kernel(const float* __restrict__ a0, const float* __restrict__ a1,
                                 const float* __restrict__ a2, const float* __restrict__ a3,
                                 const float* __restrict__ a4, const float* __restrict__ a5,
                                 const float* __restrict__ a6, const float* __restrict__ a7,
                                 const float* __restrict__ a8, unsigned short* __restrict__ out)
{
  const int i = blockIdx.x * 256 + threadIdx.x;
  if (i >= NGRP_ALL) return;
  if (i >= NGRP_REORD) {                       // out_w padded fragment tile
    const int g  = i - NGRP_REORD;             // [0, 1024)
    const int ks = g >> 6;
    const int ln = g & 63;
    const int col = ln & 31;
    const int kg  = ln >> 5;
    #pragma unroll
    for (int j = 0; j < 8; ++j) {
      const float vv = (col < 4) ? a8[col * 256 + ks * 16 + kg * 8 + j] : 0.f;
      out[OFF_WOUT + (size_t)g * 8 + j] = f2bfu(vv);
    }
    return;
  }
  const float* src; int off, Kd, g;
  if      (i < 6144)  { src = a0; off = OFF_WSW1; Kd = 192; g = i; }
  else if (i < 12288) { src = a1; off = OFF_WSS1; Kd = 192; g = i - 6144; }
  else if (i < 18432) { src = a2; off = OFF_WSG1; Kd = 192; g = i - 12288; }
  else if (i < 26624) { src = a3; off = OFF_WSC1; Kd = 256; g = i - 18432; }
  else if (i < 34816) { src = a4; off = OFF_WSW2; Kd = 256; g = i - 26624; }
  else if (i < 43008) { src = a5; off = OFF_WSS2; Kd = 256; g = i - 34816; }
  else if (i < 51200) { src = a6; off = OFF_WSG2; Kd = 256; g = i - 43008; }
  else                { src = a7; off = OFF_WSC2; Kd = 256; g = i - 51200; }
  const int KS   = Kd >> 4;
  const int tile = g / (KS * 64);
  const int rem  = g - tile * (KS * 64);
  const int ks   = rem >> 6;
  const int ln   = rem & 63;
  const float* sp = src + (size_t)(tile * 32 + (ln & 31)) * Kd + ks * 16 + (ln >> 5) * 8;
  #pragma unroll
  for (int j = 0; j < 8; ++j) out[off + (size_t)g * 8 + j] = f2bfu(sp[j]);
}

// ---- 3-way shared-A pass: u,s,g = x @ {Wsw,Wss,Wsg}^T for BOTH m-tiles ----
// One A-read feeds 6 MFMA; weight loads shared across m-tiles (key for L2).
// b = silu(u)*s -> sOut; gate sigmoid packed to sg0/sg1.
template<int KS>
static __device__ __forceinline__ void bgphase(const unsigned short* __restrict__ Wsw,
                                               const unsigned short* __restrict__ Wss,
                                               const unsigned short* __restrict__ Wsg,
                                               const unsigned short* __restrict__ sIn,
                                               unsigned short* __restrict__ sOut,
                                               int l31, int kg, int xr, int ocol, float bias,
                                               unsigned (&sg0)[8], unsigned (&sg1)[8])
{
  f32x16 u0{}, u1{}, s0{}, s1{}, g0{}, g1{};
  #pragma unroll 2
  for (int ks = 0; ks < KS; ++ks) {
    const bf16x8 wa = *(const bf16x8*)(Wsw + ks * 512);
    const bf16x8 wb = *(const bf16x8*)(Wss + ks * 512);
    const bf16x8 wg = *(const bf16x8*)(Wsg + ks * 512);
    const int off = ((ks * 16) + kg * 8) ^ xr;
    const bf16x8 A0 = *(const bf16x8*)(sIn + l31 * LSTR + off);
    const bf16x8 A1 = *(const bf16x8*)(sIn + (32 + l31) * LSTR + off);
    u0 = mfma32(A0, wa, u0); u1 = mfma32(A1, wa, u1);
    s0 = mfma32(A0, wb, s0); s1 = mfma32(A1, wb, s1);
    g0 = mfma32(A0, wg, g0); g1 = mfma32(A1, wg, g1);
  }
  #pragma unroll
  for (int i = 0; i < 16; ++i) {
    const float x0 = u0[i];
    const float x1 = u1[i];
    sOut[lidx(crow(i, kg),      ocol)] = f2bfu(x0 * sigm(x0) * s0[i]);
    sOut[lidx(32 + crow(i, kg), ocol)] = f2bfu(x1 * sigm(x1) * s1[i]);
  }
  #pragma unroll
  for (int p = 0; p < 8; ++p) {
    sg0[p] = pk2(sigm(g0[2*p] + bias), sigm(g0[2*p+1] + bias));
    sg1[p] = pk2(sigm(g1[2*p] + bias), sigm(g1[2*p+1] + bias));
  }
}

// ---- scale pass: c = b @ Wc^T (both m-tiles); x = [x +] sg*c -> packed + sA ----
template<int RES>
static __device__ __forceinline__ void scphase(const unsigned short* __restrict__ Wc,
                                               const unsigned short* __restrict__ sBin,
                                               unsigned short* __restrict__ sAout,
                                               int l31, int kg, int xr, int ocol,
                                               const unsigned (&sg0)[8], const unsigned (&sg1)[8],
                                               unsigned (&x0)[8], unsigned (&x1)[8])
{
  f32x16 c0{}, c1{};
  #pragma unroll 4
  for (int ks = 0; ks < 16; ++ks) {
    const bf16x8 wv = *(const bf16x8*)(Wc + ks * 512);
    const int off = ((ks * 16) + kg * 8) ^ xr;
    const bf16x8 A0 = *(const bf16x8*)(sBin + l31 * LSTR + off);
    const bf16x8 A1 = *(const bf16x8*)(sBin + (32 + l31) * LSTR + off);
    c0 = mfma32(A0, wv, c0);
    c1 = mfma32(A1, wv, c1);
  }
  #pragma unroll
  for (int p = 0; p < 8; ++p) {
    const float ya0 = lo16(sg0[p]) * c0[2*p],  ya1 = hi16(sg0[p]) * c0[2*p+1];
    const float yb0 = lo16(sg1[p]) * c1[2*p],  yb1 = hi16(sg1[p]) * c1[2*p+1];
    if (RES) {
      x0[p] = pk2(lo16(x0[p]) + ya0, hi16(x0[p]) + ya1);
      x1[p] = pk2(lo16(x1[p]) + yb0, hi16(x1[p]) + yb1);
    } else {
      x0[p] = pk2(ya0, ya1);
      x1[p] = pk2(yb0, yb1);
    }
    const int r0 = crow(2 * p, kg);
    sAout[lidx(r0,          ocol)] = (unsigned short)(x0[p] & 0xffff);
    sAout[lidx(r0 + 1,      ocol)] = (unsigned short)(x0[p] >> 16);
    sAout[lidx(32 + r0,     ocol)] = (unsigned short)(x1[p] & 0xffff);
    sAout[lidx(32 + r0 + 1, ocol)] = (unsigned short)(x1[p] >> 16);
  }
}

// accumulate sum / sum-of-squares over one packed chunk (8 bf16 values)
#define LNACC(P) { \
  float e_; \
  e_ = bfu2f(P[0]); s += e_; sq += e_ * e_; \
  e_ = bfu2f(P[1]); s += e_; sq += e_ * e_; \
  e_ = bfu2f(P[2]); s += e_; sq += e_ * e_; \
  e_ = bfu2f(P[3]); s += e_; sq += e_ * e_; \
  e_ = bfu2f(P[4]); s += e_; sq += e_ * e_; \
  e_ = bfu2f(P[5]); s += e_; sq += e_ * e_; \
  e_ = bfu2f(P[6]); s += e_; sq += e_ * e_; \
  e_ = bfu2f(P[7]); s += e_; sq += e_ * e_; }

// normalize one packed chunk with gamma/beta at GPTR/BPTR+base, store to sA
#define LNNORM(P, GPTR, BPTR, BASE) { \
  const int base_ = (BASE); \
  const float4 ga_ = *(const float4*)((GPTR) + base_); \
  const float4 gb_ = *(const float4*)((GPTR) + base_ + 4); \
  const float4 oa_ = *(const float4*)((BPTR) + base_); \
  const float4 ob_ = *(const float4*)((BPTR) + base_ + 4); \
  u16x8 q_; \
  q_[0] = f2bfu((bfu2f(P[0]) - mean) * rstd * ga_.x + oa_.x); \
  q_[1] = f2bfu((bfu2f(P[1]) - mean) * rstd * ga_.y + oa_.y); \
  q_[2] = f2bfu((bfu2f(P[2]) - mean) * rstd * ga_.z + oa_.z); \
  q_[3] = f2bfu((bfu2f(P[3]) - mean) * rstd * ga_.w + oa_.w); \
  q_[4] = f2bfu((bfu2f(P[4]) - mean) * rstd * gb_.x + ob_.x); \
  q_[5] = f2bfu((bfu2f(P[5]) - mean) * rstd * gb_.y + ob_.y); \
  q_[6] = f2bfu((bfu2f(P[6]) - mean) * rstd * gb_.z + ob_.z); \
  q_[7] = f2bfu((bfu2f(P[7]) - mean) * rstd * gb_.w + ob_.w); \
  *(u16x8*)(sA + r * LSTR + (base_ ^ xrr)) = q_; }

// ---------------------------------------------------------------------------
// Main fused kernel. 64 rows/block, 256 threads (4 waves), 64 KB LDS.
// __launch_bounds__(256,2): ~256-reg/wave budget -> NO spills possible at
// ~180 peak live (96 acc + ~85 arch); 2 blocks/CU (8 waves).
// Wave w owns ocols [64w,64w+64) as 2 col-tiles; BOTH 32-row m-tiles are
// processed inside each k-loop so weight fetches are shared (halves the L2
// weight stream vs 32-row blocks: ~29 GB -> ~14.5 GB).
// 3-way bg-pass (sw/ss/sg share one A-read: 6 MFMA per ds_read_b128).
// ---------------------------------------------------------------------------
__global__ __launch_bounds__(THREADS, 2)
void iab_rows_mfma(
    const float* __restrict__ v, const float* __restrict__ af,
    const float* __restrict__ fw, const float* __restrict__ fb,
    const float* __restrict__ ln1g, const float* __restrict__ ln1b,
    const float* __restrict__ bsig1,
    const float* __restrict__ ln2g, const float* __restrict__ ln2b,
    const float* __restrict__ bsig2,
    const float* __restrict__ outb,
    const unsigned short* __restrict__ wc,
    float* __restrict__ scores, int N)
{
  __shared__ __align__(16) unsigned short sA[ROWS * LSTR];  // xhat1 -> x2 -> xhat2 -> xf
  __shared__ __align__(16) unsigned short sB[ROWS * LSTR];  // b1 -> b2

  const int t    = threadIdx.x;
  const int w    = t >> 6;
  const int lane = t & 63;
  const int l31  = lane & 31;
  const int kg   = lane >> 5;
  const int xr   = (lane & 7) << 3;
  const int row0 = blockIdx.x * ROWS;
  const int oc0  = w * 64 + l31;
  const int oc1  = oc0 + 32;
  const int T0   = w * 2;
  const int T1   = w * 2 + 1;
  const int lb   = lane * 8;

  // ---- P0: features + LN1, 8 threads per row, 2 sequential row-batches ----
  #pragma unroll 1
  for (int it = 0; it < 2; ++it) {
    const int r   = (t >> 3) + it * 32;      // 0..63
    const int sub = t & 7;
    const int g   = row0 + r;
    const int xrr = (r & 7) << 3;
    float s = 0.f, sq = 0.f;
    u16x8 p0, p1 = {}, p2 = {};
    {
      float vx = 0.f, vy = 0.f, vz = 0.f;
      if (g < N) {
        vx = v[3 * (size_t)g + 0];
        vy = v[3 * (size_t)g + 1];
        vz = v[3 * (size_t)g + 2];
      }
      const float nrm = sqrtf(vx * vx + vy * vy + vz * vz);
      const float4 fwa = *(const float4*)(fw + sub * 8);
      const float4 fwb = *(const float4*)(fw + sub * 8 + 4);
      const float4 fba = *(const float4*)(fb + sub * 8);
      const float4 fbb = *(const float4*)(fb + sub * 8 + 4);
      const float e0 = __cosf(6.283185307179586f * (nrm * fwa.x + fba.x));
      const float e1 = __cosf(6.283185307179586f * (nrm * fwa.y + fba.y));
      const float e2 = __cosf(6.283185307179586f * (nrm * fwa.z + fba.z));
      const float e3 = __cosf(6.283185307179586f * (nrm * fwa.w + fba.w));
      const float e4 = __cosf(6.283185307179586f * (nrm * fwb.x + fbb.x));
      const float e5 = __cosf(6.283185307179586f * (nrm * fwb.y + fbb.y));
      const float e6 = __cosf(6.283185307179586f * (nrm * fwb.z + fbb.z));
      const float e7 = __cosf(6.283185307179586f * (nrm * fwb.w + fbb.w));
      s  += e0 + e1 + e2 + e3 + e4 + e5 + e6 + e7;
      sq += e0*e0 + e1*e1 + e2*e2 + e3*e3 + e4*e4 + e5*e5 + e6*e6 + e7*e7;
      p0[0] = f2bfu(e0); p0[1] = f2bfu(e1); p0[2] = f2bfu(e2); p0[3] = f2bfu(e3);
      p0[4] = f2bfu(e4); p0[5] = f2bfu(e5); p0[6] = f2bfu(e6); p0[7] = f2bfu(e7);
    }
    if (g < N) {
      const float* ap = af + (size_t)g * 128 + sub * 8;
      {
        const float4 a0 = *(const float4*)(ap);
        const float4 a1 = *(const float4*)(ap + 4);
        s  += a0.x + a0.y + a0.z + a0.w + a1.x + a1.y + a1.z + a1.w;
        sq += a0.x*a0.x + a0.y*a0.y + a0.z*a0.z + a0.w*a0.w
            + a1.x*a1.x + a1.y*a1.y + a1.z*a1.z + a1.w*a1.w;
        p1[0] = f2bfu(a0.x); p1[1] = f2bfu(a0.y); p1[2] = f2bfu(a0.z); p1[3] = f2bfu(a0.w);
        p1[4] = f2bfu(a1.x); p1[5] = f2bfu(a1.y); p1[6] = f2bfu(a1.z); p1[7] = f2bfu(a1.w);
      }
      {
        const float4 a2 = *(const float4*)(ap + 64);
        const float4 a3 = *(const float4*)(ap + 68);
        s  += a2.x + a2.y + a2.z + a2.w + a3.x + a3.y + a3.z + a3.w;
        sq += a2.x*a2.x + a2.y*a2.y + a2.z*a2.z + a2.w*a2.w
            + a3.x*a3.x + a3.y*a3.y + a3.z*a3.z + a3.w*a3.w;
        p2[0] = f2bfu(a2.x); p2[1] = f2bfu(a2.y); p2[2] = f2bfu(a2.z); p2[3] = f2bfu(a2.w);
        p2[4] = f2bfu(a3.x); p2[5] = f2bfu(a3.y); p2[6] = f2bfu(a3.z); p2[7] = f2bfu(a3.w);
      }
    }
    #pragma unroll
    for (int o = 1; o < 8; o <<= 1) {
      s  += __shfl_xor(s,  o);
      sq += __shfl_xor(sq, o);
    }
    const float mean = s * (1.f / 192.f);
    const float var  = fmaxf(sq * (1.f / 192.f) - mean * mean, 0.f);
    const float rstd = rsqrtf(var + 1e-5f);
    LNNORM(p0, ln1g, ln1b, sub * 8);
    LNNORM(p1, ln1g, ln1b, 64 + sub * 8);
    LNNORM(p2, ln1g, ln1b, 128 + sub * 8);
  }
  __syncthreads();

  unsigned xT0M0[8], xT0M1[8], xT1M0[8], xT1M1[8];   // packed x2 -> xf
  unsigned gT0M0[8], gT0M1[8], gT1M0[8], gT1M1[8];   // packed sigmoid gates

  // ---- TB1 bg: u,s,g = xhat1 @ {Wsw1,Wss1,Wsg1}; b1 -> sB; gates -> regs ----
  bgphase<12>(wc + OFF_WSW1 + T0 * 12 * 512 + lb,
              wc + OFF_WSS1 + T0 * 12 * 512 + lb,
              wc + OFF_WSG1 + T0 * 12 * 512 + lb,
              sA, sB, l31, kg, xr, oc0, bsig1[oc0], gT0M0, gT0M1);
  __builtin_amdgcn_sched_barrier(0);
  bgphase<12>(wc + OFF_WSW1 + T1 * 12 * 512 + lb,
              wc + OFF_WSS1 + T1 * 12 * 512 + lb,
              wc + OFF_WSG1 + T1 * 12 * 512 + lb,
              sA, sB, l31, kg, xr, oc1, bsig1[oc1], gT1M0, gT1M1);
  __syncthreads();   // b1 visible; ALL xhat1 reads complete -> sA reusable

  // ---- TB1 sc: c = b1 @ Wsc1; x2 = sig*c -> regs + sA ----
  scphase<0>(wc + OFF_WSC1 + T0 * 16 * 512 + lb, sB, sA,
             l31, kg, xr, oc0, gT0M0, gT0M1, xT0M0, xT0M1);
  __builtin_amdgcn_sched_barrier(0);
  scphase<0>(wc + OFF_WSC1 + T1 * 16 * 512 + lb, sB, sA,
             l31, kg, xr, oc1, gT1M0, gT1M1, xT1M0, xT1M1);
  __syncthreads();   // x2 visible in sA

  // ---- LN2: 8 threads per row, chunked, 2 sequential row-batches ----
  #pragma unroll 1
  for (int it = 0; it < 2; ++it) {
    const int r   = (t >> 3) + it * 32;
    const int sub = t & 7;
    const int xrr = (r & 7) << 3;
    const u16x8 rv0 = *(const u16x8*)(sA + r * LSTR + ((sub * 32 +  0) ^ xrr));
    const u16x8 rv1 = *(const u16x8*)(sA + r * LSTR + ((sub * 32 +  8) ^ xrr));
    const u16x8 rv2 = *(const u16x8*)(sA + r * LSTR + ((sub * 32 + 16) ^ xrr));
    const u16x8 rv3 = *(const u16x8*)(sA + r * LSTR + ((sub * 32 + 24) ^ xrr));
    float s = 0.f, sq = 0.f;
    LNACC(rv0);
    LNACC(rv1);
    LNACC(rv2);
    LNACC(rv3);
    #pragma unroll
    for (int o = 1; o < 8; o <<= 1) {
      s  += __shfl_xor(s,  o);
      sq += __shfl_xor(sq, o);
    }
    const float mean = s * (1.f / 256.f);
    const float var  = fmaxf(sq * (1.f / 256.f) - mean * mean, 0.f);
    const float rstd = rsqrtf(var + 1e-5f);
    LNNORM(rv0, ln2g, ln2b, sub * 32 +  0);
    LNNORM(rv1, ln2g, ln2b, sub * 32 +  8);
    LNNORM(rv2, ln2g, ln2b, sub * 32 + 16);
    LNNORM(rv3, ln2g, ln2b, sub * 32 + 24);
  }
  __syncthreads();

  // ---- TB2 bg: u2,s2,g2 = xhat2 @ {Wsw2,Wss2,Wsg2}; b2 -> sB; gates ----
  bgphase<16>(wc + OFF_WSW2 + T0 * 16 * 512 + lb,
              wc + OFF_WSS2 + T0 * 16 * 512 + lb,
              wc + OFF_WSG2 + T0 * 16 * 512 + lb,
              sA, sB, l31, kg, xr, oc0, bsig2[oc0], gT0M0, gT0M1);
  __builtin_amdgcn_sched_barrier(0);
  bgphase<16>(wc + OFF_WSW2 + T1 * 16 * 512 + lb,
              wc + OFF_WSS2 + T1 * 16 * 512 + lb,
              wc + OFF_WSG2 + T1 * 16 * 512 + lb,
              sA, sB, l31, kg, xr, oc1, bsig2[oc1], gT1M0, gT1M1);
  __syncthreads();   // b2 visible; ALL xhat2 reads complete

  // ---- TB2 sc: c2 = b2 @ Wsc2; xf = x2 + sig2*c2 -> sA ----
  scphase<1>(wc + OFF_WSC2 + T0 * 16 * 512 + lb, sB, sA,
             l31, kg, xr, oc0, gT0M0, gT0M1, xT0M0, xT0M1);
  __builtin_amdgcn_sched_barrier(0);
  scphase<1>(wc + OFF_WSC2 + T1 * 16 * 512 + lb, sB, sA,
             l31, kg, xr, oc1, gT1M0, gT1M1, xT1M0, xT1M1);
  __syncthreads();   // xf visible

  // ---- F: scores = xf @ out_w^T + out_b via MFMA (waves 0-1) ----
  if (w < 2) {
    const unsigned short* WtF = wc + OFF_WOUT + (size_t)lane * 8;
    f32x16 c{};
    #pragma unroll 4
    for (int ks = 0; ks < 16; ++ks) {
      const bf16x8 wf = *(const bf16x8*)(WtF + ks * 512);
      const bf16x8 A  = *(const bf16x8*)(sA + (w * 32 + l31) * LSTR + (((ks * 16) + kg * 8) ^ xr));
      c = mfma32(A, wf, c);
    }
    if (l31 < 4) {
      const float bias = outb[l31];
      #pragma unroll
      for (int i = 0; i < 16; ++i) {
        const int g = row0 + w * 32 + crow(i, kg);
        if (g < N) scores[(size_t)g * 4 + l31] = c[i] + bias;
      }
    }
  }
}

// ---------------------------------------------------------------------------
// Segment softmax + weighted 3-vector pooling (sorted indices, wave/segment).
// ---------------------------------------------------------------------------
__device__ __forceinline__ int iab_lower_bound(const int* __restrict__ a, int n, int key)
{
  int lo = 0, hi = n;
  while (lo < hi) {
    const int mid = (lo + hi) >> 1;
    if (a[mid] < key) lo = mid + 1; else hi = mid;
  }
  return lo;
}

__global__ __launch_bounds__(256)
void iab_segpool_kernel(const float* __restrict__ scores,
                        const float* __restrict__ v,
                        const int* __restrict__ gidx,
                        float* __restrict__ out, int N, int E)
{
  const int seg  = blockIdx.x * 4 + (threadIdx.x >> 6);
  const int lane = threadIdx.x & 63;
  if (seg >= E) return;

  const int lo = iab_lower_bound(gidx, N, seg);
  const int hi = iab_lower_bound(gidx, N, seg + 1);

  const int h  = lane & 3;
  const int ro = lane >> 2;

  float m = -INFINITY;
  for (int base = lo; base < hi; base += 16) {
    const int r = base + ro;
    if (r < hi) m = fmaxf(m, scores[(size_t)r * 4 + h]);
  }
  #pragma unroll
  for (int o = 4; o < 64; o <<= 1) m = fmaxf(m, __shfl_xor(m, o));

  float ssum = 0.f, w0 = 0.f, w1 = 0.f, w2 = 0.f;
  for (int base = lo; base < hi; base += 16) {
    const int r = base + ro;
    if (r < hi) {
      const float e = expf(scores[(size_t)r * 4 + h] - m);
      ssum += e;
      w0 += e * v[3 * (size_t)r + 0];
      w1 += e * v[3 * (size_t)r + 1];
      w2 += e * v[3 * (size_t)r + 2];
    }
  }
  #pragma unroll
  for (int o = 4; o < 64; o <<= 1) {
    ssum += __shfl_xor(ssum, o);
    w0   += __shfl_xor(w0, o);
    w1   += __shfl_xor(w1, o);
    w2   += __shfl_xor(w2, o);
  }

  if (ro == 0) {
    const float inv = (hi > lo) ? (1.f / ssum) : 0.f;
    out[(size_t)seg * 12 + h * 3 + 0] = w0 * inv;
    out[(size_t)seg * 12 + h * 3 + 1] = w1 * inv;
    out[(size_t)seg * 12 + h * 3 + 2] = w2 * inv;
  }
}

// ---------------------------------------------------------------------------
extern "C" void kernel_launch(void* const* d_in, const int* in_sizes, int n_in,
                              void* d_out, int out_size, void* d_ws, size_t ws_size,
                              hipStream_t stream)
{
  const float* v     = (const float*)d_in[0];
  const float* af    = (const float*)d_in[1];
  const int*   gidx  = (const int*)  d_in[2];
  const float* fw    = (const float*)d_in[4];
  const float* fb    = (const float*)d_in[5];
  const float* ln1g  = (const float*)d_in[6];
  const float* ln1b  = (const float*)d_in[7];
  const float* wsw1  = (const float*)d_in[8];
  const float* wss1  = (const float*)d_in[9];
  const float* wsig1 = (const float*)d_in[10];
  const float* bsig1 = (const float*)d_in[11];
  const float* wsc1  = (const float*)d_in[12];
  const float* ln2g  = (const float*)d_in[13];
  const float* ln2b  = (const float*)d_in[14];
  const float* wsw2  = (const float*)d_in[15];
  const float* wss2  = (const float*)d_in[16];
  const float* wsig2 = (const float*)d_in[17];
  const float* bsig2 = (const float*)d_in[18];
  const float* wsc2  = (const float*)d_in[19];
  const float* outw  = (const float*)d_in[20];
  const float* outb  = (const float*)d_in[21];

  const int N = in_sizes[0] / 3;
  const int E = out_size / 12;

  float* scores = (float*)d_ws;                                   // N*4 f32 = 16 MB
  unsigned short* wcv = (unsigned short*)((char*)d_ws + (size_t)N * 4 * sizeof(float));

  hipLaunchKernelGGL(iab_wconv_kernel, dim3((NGRP_ALL + 255) / 256), dim3(256), 0, stream,
                     wsw1, wss1, wsig1, wsc1, wsw2, wss2, wsig2, wsc2, outw, wcv);

  hipLaunchKernelGGL(iab_rows_mfma, dim3((N + ROWS - 1) / ROWS), dim3(THREADS), 0, stream,
                     v, af, fw, fb, ln1g, ln1b, bsig1, ln2g, ln2b, bsig2, outb,
                     wcv, scores, N);

  hipLaunchKernelGGL(iab_segpool_kernel, dim3((E + 3) / 4), dim3(256), 0, stream,
                     scores, v, gidx, (float*)d_out, N, E);
}

// Round 13
// 2079.719 us; speedup vs baseline: 1.1622x; 1.1622x over previous
//
#include <hip/hip_runtime.h>
#include <math.h>

#define DIN   192
#define HD    256
#define ROWS  64
#define THREADS 256
#define LSTR  256

typedef __bf16 bf16_t;
typedef bf16_t bf16x8 __attribute__((ext_vector_type(8)));
typedef unsigned short u16x8 __attribute__((ext_vector_type(8)));
typedef float  f32x16 __attribute__((ext_vector_type(16)));

static __device__ __forceinline__ f32x16 mfma32(bf16x8 a, bf16x8 b, f32x16 c) {
  return __builtin_amdgcn_mfma_f32_32x32x16_bf16(a, b, c, 0, 0, 0);
}
static __device__ __forceinline__ unsigned short f2bfu(float f) {
  bf16_t h = (bf16_t)f; unsigned short u; __builtin_memcpy(&u, &h, 2); return u;
}
static __device__ __forceinline__ float bfu2f(unsigned short u) {
  unsigned x = ((unsigned)u) << 16; float f; __builtin_memcpy(&f, &x, 4); return f;
}
static __device__ __forceinline__ unsigned pk2(float a, float b) {
  return (unsigned)f2bfu(a) | ((unsigned)f2bfu(b) << 16);
}
static __device__ __forceinline__ float lo16(unsigned u) { return bfu2f((unsigned short)(u & 0xffff)); }
static __device__ __forceinline__ float hi16(unsigned u) { return bfu2f((unsigned short)(u >> 16)); }
static __device__ __forceinline__ float sigm(float x) {
  return __builtin_amdgcn_rcpf(1.f + __expf(-x));
}
// XOR-swizzled LDS element index (b16 granularity)
static __device__ __forceinline__ int lidx(int row, int col) {
  return row * LSTR + (col ^ ((row & 7) << 3));
}
// C-layout row for 32x32 MFMA (m74/m101): row = (r&3) + 8*(r>>2) + 4*kg
static __device__ __forceinline__ int crow(int r, int kg) {
  return (r & 3) + 8 * (r >> 2) + 4 * kg;
}

// bf16 weight regions (elements) in d_ws after scores buffer.
// Fragment order: ((tile*KS + ks)*64 + lane)*8 + j; tile=ocol>>5,
// lane=kg*32+(ocol&31), k=ks*16+kg*8+j. out_w padded 4->32 cols.
#define OFF_WSW1 0
#define OFF_WSS1 49152
#define OFF_WSG1 98304
#define OFF_WSC1 147456
#define OFF_WSW2 212992
#define OFF_WSS2 278528
#define OFF_WSG2 344064
#define OFF_WSC2 409600
#define OFF_WOUT 475136
#define NGRP_REORD 59392
#define NGRP_ALL   60416

__global__ void iab_wconv_kernel(const float* __restrict__ a0, const float* __restrict__ a1,
                                 const float* __restrict__ a2, const float* __restrict__ a3,
                                 const float* __restrict__ a4, const float* __restrict__ a5,
                                 const float* __restrict__ a6, const float* __restrict__ a7,
                                 const float* __restrict__ a8, unsigned short* __restrict__ out)
{
  const int i = blockIdx.x * 256 + threadIdx.x;
  if (i >= NGRP_ALL) return;
  if (i >= NGRP_REORD) {                       // out_w padded fragment tile
    const int g  = i - NGRP_REORD;             // [0, 1024)
    const int ks = g >> 6;
    const int ln = g & 63;
    const int col = ln & 31;
    const int kg  = ln >> 5;
    #pragma unroll
    for (int j = 0; j < 8; ++j) {
      const float vv = (col < 4) ? a8[col * 256 + ks * 16 + kg * 8 + j] : 0.f;
      out[OFF_WOUT + (size_t)g * 8 + j] = f2bfu(vv);
    }
    return;
  }
  const float* src; int off, Kd, g;
  if      (i < 6144)  { src = a0; off = OFF_WSW1; Kd = 192; g = i; }
  else if (i < 12288) { src = a1; off = OFF_WSS1; Kd = 192; g = i - 6144; }
  else if (i < 18432) { src = a2; off = OFF_WSG1; Kd = 192; g = i - 12288; }
  else if (i < 26624) { src = a3; off = OFF_WSC1; Kd = 256; g = i - 18432; }
  else if (i < 34816) { src = a4; off = OFF_WSW2; Kd = 256; g = i - 26624; }
  else if (i < 43008) { src = a5; off = OFF_WSS2; Kd = 256; g = i - 34816; }
  else if (i < 51200) { src = a6; off = OFF_WSG2; Kd = 256; g = i - 43008; }
  else                { src = a7; off = OFF_WSC2; Kd = 256; g = i - 51200; }
  const int KS   = Kd >> 4;
  const int tile = g / (KS * 64);
  const int rem  = g - tile * (KS * 64);
  const int ks   = rem >> 6;
  const int ln   = rem & 63;
  const float* sp = src + (size_t)(tile * 32 + (ln & 31)) * Kd + ks * 16 + (ln >> 5) * 8;
  #pragma unroll
  for (int j = 0; j < 8; ++j) out[off + (size_t)g * 8 + j] = f2bfu(sp[j]);
}

// ---- paired b-phase, BOTH m-tiles: b = silu(x@Wsw)*(x@Wss) -> sOut ----
// 4 accumulators (64 acc regs); weight loads shared across m-tiles.
template<int KS>
static __device__ __forceinline__ void bphase2(const unsigned short* __restrict__ Wsw,
                                               const unsigned short* __restrict__ Wss,
                                               const unsigned short* __restrict__ sIn,
                                               unsigned short* __restrict__ sOut,
                                               int l31, int kg, int xr, int ocol)
{
  f32x16 u0{}, u1{}, s0{}, s1{};
  #pragma unroll 2
  for (int ks = 0; ks < KS; ++ks) {
    const bf16x8 wa = *(const bf16x8*)(Wsw + ks * 512);
    const bf16x8 wb = *(const bf16x8*)(Wss + ks * 512);
    const int off = ((ks * 16) + kg * 8) ^ xr;
    const bf16x8 A0 = *(const bf16x8*)(sIn + l31 * LSTR + off);
    const bf16x8 A1 = *(const bf16x8*)(sIn + (32 + l31) * LSTR + off);
    u0 = mfma32(A0, wa, u0); u1 = mfma32(A1, wa, u1);
    s0 = mfma32(A0, wb, s0); s1 = mfma32(A1, wb, s1);
  }
  #pragma unroll
  for (int i = 0; i < 16; ++i) {
    const float x0 = u0[i];
    const float x1 = u1[i];
    sOut[lidx(crow(i, kg),      ocol)] = f2bfu(x0 * sigm(x0) * s0[i]);
    sOut[lidx(32 + crow(i, kg), ocol)] = f2bfu(x1 * sigm(x1) * s1[i]);
  }
}

// ---- c-phase, BOTH m-tiles, gate then scale SEQUENTIALLY (<=32 acc live):
// x = [x +] sigmoid(xhat@Wg + bias) * (b@Wc)   (packed bf16x2 in x0/x1)
template<int KSG, int RES>
static __device__ __forceinline__ void cphase2(const unsigned short* __restrict__ Wg,
                                               const unsigned short* __restrict__ Wc,
                                               const unsigned short* __restrict__ sAin,
                                               const unsigned short* __restrict__ sBin,
                                               int l31, int kg, int xr, float bias,
                                               unsigned (&x0)[8], unsigned (&x1)[8])
{
  unsigned pg0[8], pg1[8];
  {
    f32x16 g0{}, g1{};
    #pragma unroll 4
    for (int ks = 0; ks < KSG; ++ks) {
      const bf16x8 wg = *(const bf16x8*)(Wg + ks * 512);
      const int off = ((ks * 16) + kg * 8) ^ xr;
      const bf16x8 A0 = *(const bf16x8*)(sAin + l31 * LSTR + off);
      const bf16x8 A1 = *(const bf16x8*)(sAin + (32 + l31) * LSTR + off);
      g0 = mfma32(A0, wg, g0);
      g1 = mfma32(A1, wg, g1);
    }
    #pragma unroll
    for (int p = 0; p < 8; ++p) {
      pg0[p] = pk2(sigm(g0[2*p] + bias), sigm(g0[2*p+1] + bias));
      pg1[p] = pk2(sigm(g1[2*p] + bias), sigm(g1[2*p+1] + bias));
    }
  }
  {
    f32x16 c0{}, c1{};
    #pragma unroll 4
    for (int ks = 0; ks < 16; ++ks) {
      const bf16x8 wv = *(const bf16x8*)(Wc + ks * 512);
      const int off = ((ks * 16) + kg * 8) ^ xr;
      const bf16x8 A0 = *(const bf16x8*)(sBin + l31 * LSTR + off);
      const bf16x8 A1 = *(const bf16x8*)(sBin + (32 + l31) * LSTR + off);
      c0 = mfma32(A0, wv, c0);
      c1 = mfma32(A1, wv, c1);
    }
    #pragma unroll
    for (int p = 0; p < 8; ++p) {
      const float ya0 = lo16(pg0[p]) * c0[2*p],  ya1 = hi16(pg0[p]) * c0[2*p+1];
      const float yb0 = lo16(pg1[p]) * c1[2*p],  yb1 = hi16(pg1[p]) * c1[2*p+1];
      if (RES) {
        x0[p] = pk2(lo16(x0[p]) + ya0, hi16(x0[p]) + ya1);
        x1[p] = pk2(lo16(x1[p]) + yb0, hi16(x1[p]) + yb1);
      } else {
        x0[p] = pk2(ya0, ya1);
        x1[p] = pk2(yb0, yb1);
      }
    }
  }
}

// write packed x (both m-tiles) to sA
static __device__ __forceinline__ void storePk2(unsigned short* dst,
                                                const unsigned (&x0)[8], const unsigned (&x1)[8],
                                                int kg, int ocol)
{
  #pragma unroll
  for (int p = 0; p < 8; ++p) {
    const int r0 = crow(2 * p, kg);
    dst[lidx(r0,          ocol)] = (unsigned short)(x0[p] & 0xffff);
    dst[lidx(r0 + 1,      ocol)] = (unsigned short)(x0[p] >> 16);
    dst[lidx(32 + r0,     ocol)] = (unsigned short)(x1[p] & 0xffff);
    dst[lidx(32 + r0 + 1, ocol)] = (unsigned short)(x1[p] >> 16);
  }
}

// accumulate sum / sum-of-squares over one packed chunk (8 bf16 values)
#define LNACC(P) { \
  float e_; \
  e_ = bfu2f(P[0]); s += e_; sq += e_ * e_; \
  e_ = bfu2f(P[1]); s += e_; sq += e_ * e_; \
  e_ = bfu2f(P[2]); s += e_; sq += e_ * e_; \
  e_ = bfu2f(P[3]); s += e_; sq += e_ * e_; \
  e_ = bfu2f(P[4]); s += e_; sq += e_ * e_; \
  e_ = bfu2f(P[5]); s += e_; sq += e_ * e_; \
  e_ = bfu2f(P[6]); s += e_; sq += e_ * e_; \
  e_ = bfu2f(P[7]); s += e_; sq += e_ * e_; }

// normalize one packed chunk with gamma/beta at GPTR/BPTR+base, store to sA
#define LNNORM(P, GPTR, BPTR, BASE) { \
  const int base_ = (BASE); \
  const float4 ga_ = *(const float4*)((GPTR) + base_); \
  const float4 gb_ = *(const float4*)((GPTR) + base_ + 4); \
  const float4 oa_ = *(const float4*)((BPTR) + base_); \
  const float4 ob_ = *(const float4*)((BPTR) + base_ + 4); \
  u16x8 q_; \
  q_[0] = f2bfu((bfu2f(P[0]) - mean) * rstd * ga_.x + oa_.x); \
  q_[1] = f2bfu((bfu2f(P[1]) - mean) * rstd * ga_.y + oa_.y); \
  q_[2] = f2bfu((bfu2f(P[2]) - mean) * rstd * ga_.z + oa_.z); \
  q_[3] = f2bfu((bfu2f(P[3]) - mean) * rstd * ga_.w + oa_.w); \
  q_[4] = f2bfu((bfu2f(P[4]) - mean) * rstd * gb_.x + ob_.x); \
  q_[5] = f2bfu((bfu2f(P[5]) - mean) * rstd * gb_.y + ob_.y); \
  q_[6] = f2bfu((bfu2f(P[6]) - mean) * rstd * gb_.z + ob_.z); \
  q_[7] = f2bfu((bfu2f(P[7]) - mean) * rstd * gb_.w + ob_.w); \
  *(u16x8*)(sA + r * LSTR + (base_ ^ xrr)) = q_; }

// ---------------------------------------------------------------------------
// Main fused kernel. 64 rows/block, 256 threads (4 waves), 64 KB LDS.
// __launch_bounds__(256,2): 8 waves/CU -> 2 INDEPENDENT blocks/CU; total
// reg budget 256/wave, compiler splits 128 arch + 128 acc (measured across
// R7-R12: total = 2048/wavesPerSIMD, even split). Phase structure keeps
// arch <=~110 (x-carry 32 + pg 16 + weights 32 + addr) and acc <=64.
// Both m-tiles inside each k-loop -> weight fetch shared (L2 stream halved).
// ---------------------------------------------------------------------------
__global__ __launch_bounds__(THREADS, 2)
void iab_rows_mfma(
    const float* __restrict__ v, const float* __restrict__ af,
    const float* __restrict__ fw, const float* __restrict__ fb,
    const float* __restrict__ ln1g, const float* __restrict__ ln1b,
    const float* __restrict__ bsig1,
    const float* __restrict__ ln2g, const float* __restrict__ ln2b,
    const float* __restrict__ bsig2,
    const float* __restrict__ outb,
    const unsigned short* __restrict__ wc,
    float* __restrict__ scores, int N)
{
  __shared__ __align__(16) unsigned short sA[ROWS * LSTR];  // xhat1 -> x2 -> xhat2 -> xf
  __shared__ __align__(16) unsigned short sB[ROWS * LSTR];  // b1 -> b2

  const int t    = threadIdx.x;
  const int w    = t >> 6;
  const int lane = t & 63;
  const int l31  = lane & 31;
  const int kg   = lane >> 5;
  const int xr   = (lane & 7) << 3;
  const int row0 = blockIdx.x * ROWS;
  const int oc0  = w * 64 + l31;
  const int oc1  = oc0 + 32;
  const int T0   = w * 2;
  const int T1   = w * 2 + 1;
  const int lb   = lane * 8;

  // ---- P0: features + LN1, 8 threads per row, 2 sequential row-batches ----
  #pragma unroll 1
  for (int it = 0; it < 2; ++it) {
    const int r   = (t >> 3) + it * 32;      // 0..63
    const int sub = t & 7;
    const int g   = row0 + r;
    const int xrr = (r & 7) << 3;
    float s = 0.f, sq = 0.f;
    u16x8 p0, p1 = {}, p2 = {};
    {
      float vx = 0.f, vy = 0.f, vz = 0.f;
      if (g < N) {
        vx = v[3 * (size_t)g + 0];
        vy = v[3 * (size_t)g + 1];
        vz = v[3 * (size_t)g + 2];
      }
      const float nrm = sqrtf(vx * vx + vy * vy + vz * vz);
      const float4 fwa = *(const float4*)(fw + sub * 8);
      const float4 fwb = *(const float4*)(fw + sub * 8 + 4);
      const float4 fba = *(const float4*)(fb + sub * 8);
      const float4 fbb = *(const float4*)(fb + sub * 8 + 4);
      const float e0 = __cosf(6.283185307179586f * (nrm * fwa.x + fba.x));
      const float e1 = __cosf(6.283185307179586f * (nrm * fwa.y + fba.y));
      const float e2 = __cosf(6.283185307179586f * (nrm * fwa.z + fba.z));
      const float e3 = __cosf(6.283185307179586f * (nrm * fwa.w + fba.w));
      const float e4 = __cosf(6.283185307179586f * (nrm * fwb.x + fbb.x));
      const float e5 = __cosf(6.283185307179586f * (nrm * fwb.y + fbb.y));
      const float e6 = __cosf(6.283185307179586f * (nrm * fwb.z + fbb.z));
      const float e7 = __cosf(6.283185307179586f * (nrm * fwb.w + fbb.w));
      s  += e0 + e1 + e2 + e3 + e4 + e5 + e6 + e7;
      sq += e0*e0 + e1*e1 + e2*e2 + e3*e3 + e4*e4 + e5*e5 + e6*e6 + e7*e7;
      p0[0] = f2bfu(e0); p0[1] = f2bfu(e1); p0[2] = f2bfu(e2); p0[3] = f2bfu(e3);
      p0[4] = f2bfu(e4); p0[5] = f2bfu(e5); p0[6] = f2bfu(e6); p0[7] = f2bfu(e7);
    }
    if (g < N) {
      const float* ap = af + (size_t)g * 128 + sub * 8;
      {
        const float4 a0 = *(const float4*)(ap);
        const float4 a1 = *(const float4*)(ap + 4);
        s  += a0.x + a0.y + a0.z + a0.w + a1.x + a1.y + a1.z + a1.w;
        sq += a0.x*a0.x + a0.y*a0.y + a0.z*a0.z + a0.w*a0.w
            + a1.x*a1.x + a1.y*a1.y + a1.z*a1.z + a1.w*a1.w;
        p1[0] = f2bfu(a0.x); p1[1] = f2bfu(a0.y); p1[2] = f2bfu(a0.z); p1[3] = f2bfu(a0.w);
        p1[4] = f2bfu(a1.x); p1[5] = f2bfu(a1.y); p1[6] = f2bfu(a1.z); p1[7] = f2bfu(a1.w);
      }
      {
        const float4 a2 = *(const float4*)(ap + 64);
        const float4 a3 = *(const float4*)(ap + 68);
        s  += a2.x + a2.y + a2.z + a2.w + a3.x + a3.y + a3.z + a3.w;
        sq += a2.x*a2.x + a2.y*a2.y + a2.z*a2.z + a2.w*a2.w
            + a3.x*a3.x + a3.y*a3.y + a3.z*a3.z + a3.w*a3.w;
        p2[0] = f2bfu(a2.x); p2[1] = f2bfu(a2.y); p2[2] = f2bfu(a2.z); p2[3] = f2bfu(a2.w);
        p2[4] = f2bfu(a3.x); p2[5] = f2bfu(a3.y); p2[6] = f2bfu(a3.z); p2[7] = f2bfu(a3.w);
      }
    }
    #pragma unroll
    for (int o = 1; o < 8; o <<= 1) {
      s  += __shfl_xor(s,  o);
      sq += __shfl_xor(sq, o);
    }
    const float mean = s * (1.f / 192.f);
    const float var  = fmaxf(sq * (1.f / 192.f) - mean * mean, 0.f);
    const float rstd = rsqrtf(var + 1e-5f);
    LNNORM(p0, ln1g, ln1b, sub * 8);
    LNNORM(p1, ln1g, ln1b, 64 + sub * 8);
    LNNORM(p2, ln1g, ln1b, 128 + sub * 8);
  }
  __syncthreads();

  unsigned xT0M0[8], xT0M1[8], xT1M0[8], xT1M1[8];   // packed x2 -> xf

  // ---- TB1 b: b1 = silu(xhat1@Wsw1)*(xhat1@Wss1) -> sB ----
  bphase2<12>(wc + OFF_WSW1 + T0 * 12 * 512 + lb,
              wc + OFF_WSS1 + T0 * 12 * 512 + lb, sA, sB, l31, kg, xr, oc0);
  __builtin_amdgcn_sched_barrier(0);
  bphase2<12>(wc + OFF_WSW1 + T1 * 12 * 512 + lb,
              wc + OFF_WSS1 + T1 * 12 * 512 + lb, sA, sB, l31, kg, xr, oc1);
  __syncthreads();   // b1 visible; xhat1 still intact in sA

  // ---- TB1 c: x2 = sig(xhat1@Wsg1+b)*(b1@Wsc1) -> packed regs ----
  cphase2<12, 0>(wc + OFF_WSG1 + T0 * 12 * 512 + lb,
                 wc + OFF_WSC1 + T0 * 16 * 512 + lb,
                 sA, sB, l31, kg, xr, bsig1[oc0], xT0M0, xT0M1);
  __builtin_amdgcn_sched_barrier(0);
  cphase2<12, 0>(wc + OFF_WSG1 + T1 * 12 * 512 + lb,
                 wc + OFF_WSC1 + T1 * 16 * 512 + lb,
                 sA, sB, l31, kg, xr, bsig1[oc1], xT1M0, xT1M1);
  __syncthreads();   // all xhat1/b1 reads complete -> sA reusable

  storePk2(sA, xT0M0, xT0M1, kg, oc0);
  storePk2(sA, xT1M0, xT1M1, kg, oc1);
  __syncthreads();   // x2 visible

  // ---- LN2: 8 threads per row, chunked, 2 sequential row-batches ----
  #pragma unroll 1
  for (int it = 0; it < 2; ++it) {
    const int r   = (t >> 3) + it * 32;
    const int sub = t & 7;
    const int xrr = (r & 7) << 3;
    const u16x8 rv0 = *(const u16x8*)(sA + r * LSTR + ((sub * 32 +  0) ^ xrr));
    const u16x8 rv1 = *(const u16x8*)(sA + r * LSTR + ((sub * 32 +  8) ^ xrr));
    const u16x8 rv2 = *(const u16x8*)(sA + r * LSTR + ((sub * 32 + 16) ^ xrr));
    const u16x8 rv3 = *(const u16x8*)(sA + r * LSTR + ((sub * 32 + 24) ^ xrr));
    float s = 0.f, sq = 0.f;
    LNACC(rv0);
    LNACC(rv1);
    LNACC(rv2);
    LNACC(rv3);
    #pragma unroll
    for (int o = 1; o < 8; o <<= 1) {
      s  += __shfl_xor(s,  o);
      sq += __shfl_xor(sq, o);
    }
    const float mean = s * (1.f / 256.f);
    const float var  = fmaxf(sq * (1.f / 256.f) - mean * mean, 0.f);
    const float rstd = rsqrtf(var + 1e-5f);
    LNNORM(rv0, ln2g, ln2b, sub * 32 +  0);
    LNNORM(rv1, ln2g, ln2b, sub * 32 +  8);
    LNNORM(rv2, ln2g, ln2b, sub * 32 + 16);
    LNNORM(rv3, ln2g, ln2b, sub * 32 + 24);
  }
  __syncthreads();

  // ---- TB2 b: b2 = silu(xhat2@Wsw2)*(xhat2@Wss2) -> sB ----
  bphase2<16>(wc + OFF_WSW2 + T0 * 16 * 512 + lb,
              wc + OFF_WSS2 + T0 * 16 * 512 + lb, sA, sB, l31, kg, xr, oc0);
  __builtin_amdgcn_sched_barrier(0);
  bphase2<16>(wc + OFF_WSW2 + T1 * 16 * 512 + lb,
              wc + OFF_WSS2 + T1 * 16 * 512 + lb, sA, sB, l31, kg, xr, oc1);
  __syncthreads();   // b2 visible; xhat2 still intact

  // ---- TB2 c: xf = x2 + sig(xhat2@Wsg2+b)*(b2@Wsc2) -> packed regs ----
  cphase2<16, 1>(wc + OFF_WSG2 + T0 * 16 * 512 + lb,
                 wc + OFF_WSC2 + T0 * 16 * 512 + lb,
                 sA, sB, l31, kg, xr, bsig2[oc0], xT0M0, xT0M1);
  __builtin_amdgcn_sched_barrier(0);
  cphase2<16, 1>(wc + OFF_WSG2 + T1 * 16 * 512 + lb,
                 wc + OFF_WSC2 + T1 * 16 * 512 + lb,
                 sA, sB, l31, kg, xr, bsig2[oc1], xT1M0, xT1M1);
  __syncthreads();   // all xhat2/b2 reads complete

  storePk2(sA, xT0M0, xT0M1, kg, oc0);
  storePk2(sA, xT1M0, xT1M1, kg, oc1);
  __syncthreads();   // xf visible

  // ---- F: scores = xf @ out_w^T + out_b via MFMA (waves 0-1) ----
  if (w < 2) {
    const unsigned short* WtF = wc + OFF_WOUT + (size_t)lane * 8;
    f32x16 c{};
    #pragma unroll 4
    for (int ks = 0; ks < 16; ++ks) {
      const bf16x8 wf = *(const bf16x8*)(WtF + ks * 512);
      const bf16x8 A  = *(const bf16x8*)(sA + (w * 32 + l31) * LSTR + (((ks * 16) + kg * 8) ^ xr));
      c = mfma32(A, wf, c);
    }
    if (l31 < 4) {
      const float bias = outb[l31];
      #pragma unroll
      for (int i = 0; i < 16; ++i) {
        const int g = row0 + w * 32 + crow(i, kg);
        if (g < N) scores[(size_t)g * 4 + l31] = c[i] + bias;
      }
    }
  }
}

// ---------------------------------------------------------------------------
// Segment softmax + weighted 3-vector pooling (sorted indices, wave/segment).
// ---------------------------------------------------------------------------
__device__ __forceinline__ int iab_lower_bound(const int* __restrict__ a, int n, int key)
{
  int lo = 0, hi = n;
  while (lo < hi) {
    const int mid = (lo + hi) >> 1;
    if (a[mid] < key) lo = mid + 1; else hi = mid;
  }
  return lo;
}

__global__ __launch_bounds__(256)
void iab_segpool_kernel(const float* __restrict__ scores,
                        const float* __restrict__ v,
                        const int* __restrict__ gidx,
                        float* __restrict__ out, int N, int E)
{
  const int seg  = blockIdx.x * 4 + (threadIdx.x >> 6);
  const int lane = threadIdx.x & 63;
  if (seg >= E) return;

  const int lo = iab_lower_bound(gidx, N, seg);
  const int hi = iab_lower_bound(gidx, N, seg + 1);

  const int h  = lane & 3;
  const int ro = lane >> 2;

  float m = -INFINITY;
  for (int base = lo; base < hi; base += 16) {
    const int r = base + ro;
    if (r < hi) m = fmaxf(m, scores[(size_t)r * 4 + h]);
  }
  #pragma unroll
  for (int o = 4; o < 64; o <<= 1) m = fmaxf(m, __shfl_xor(m, o));

  float ssum = 0.f, w0 = 0.f, w1 = 0.f, w2 = 0.f;
  for (int base = lo; base < hi; base += 16) {
    const int r = base + ro;
    if (r < hi) {
      const float e = expf(scores[(size_t)r * 4 + h] - m);
      ssum += e;
      w0 += e * v[3 * (size_t)r + 0];
      w1 += e * v[3 * (size_t)r + 1];
      w2 += e * v[3 * (size_t)r + 2];
    }
  }
  #pragma unroll
  for (int o = 4; o < 64; o <<= 1) {
    ssum += __shfl_xor(ssum, o);
    w0   += __shfl_xor(w0, o);
    w1   += __shfl_xor(w1, o);
    w2   += __shfl_xor(w2, o);
  }

  if (ro == 0) {
    const float inv = (hi > lo) ? (1.f / ssum) : 0.f;
    out[(size_t)seg * 12 + h * 3 + 0] = w0 * inv;
    out[(size_t)seg * 12 + h * 3 + 1] = w1 * inv;
    out[(size_t)seg * 12 + h * 3 + 2] = w2 * inv;
  }
}

// ---------------------------------------------------------------------------
extern "C" void kernel_launch(void* const* d_in, const int* in_sizes, int n_in,
                              void* d_out, int out_size, void* d_ws, size_t ws_size,
                              hipStream_t stream)
{
  const float* v     = (const float*)d_in[0];
  const float* af    = (const float*)d_in[1];
  const int*   gidx  = (const int*)  d_in[2];
  const float* fw    = (const float*)d_in[4];
  const float* fb    = (const float*)d_in[5];
  const float* ln1g  = (const float*)d_in[6];
  const float* ln1b  = (const float*)d_in[7];
  const float* wsw1  = (const float*)d_in[8];
  const float* wss1  = (const float*)d_in[9];
  const float* wsig1 = (const float*)d_in[10];
  const float* bsig1 = (const float*)d_in[11];
  const float* wsc1  = (const float*)d_in[12];
  const float* ln2g  = (const float*)d_in[13];
  const float* ln2b  = (const float*)d_in[14];
  const float* wsw2  = (const float*)d_in[15];
  const float* wss2  = (const float*)d_in[16];
  const float* wsig2 = (const float*)d_in[17];
  const float* bsig2 = (const float*)d_in[18];
  const float* wsc2  = (const float*)d_in[19];
  const float* outw  = (const float*)d_in[20];
  const float* outb  = (const float*)d_in[21];

  const int N = in_sizes[0] / 3;
  const int E = out_size / 12;

  float* scores = (float*)d_ws;                                   // N*4 f32 = 16 MB
  unsigned short* wcv = (unsigned short*)((char*)d_ws + (size_t)N * 4 * sizeof(float));

  hipLaunchKernelGGL(iab_wconv_kernel, dim3((NGRP_ALL + 255) / 256), dim3(256), 0, stream,
                     wsw1, wss1, wsig1, wsc1, wsw2, wss2, wsig2, wsc2, outw, wcv);

  hipLaunchKernelGGL(iab_rows_mfma, dim3((N + ROWS - 1) / ROWS), dim3(THREADS), 0, stream,
                     v, af, fw, fb, ln1g, ln1b, bsig1, ln2g, ln2b, bsig2, outb,
                     wcv, scores, N);

  hipLaunchKernelGGL(iab_segpool_kernel, dim3((E + 3) / 4), dim3(256), 0, stream,
                     scores, v, gidx, (float*)d_out, N, E);
}